// Round 1
// baseline (693.233 us; speedup 1.0000x reference)
//
#include <hip/hip_runtime.h>
#include <hip/hip_bf16.h>

typedef __bf16 bf16;
typedef __bf16 bf16x8 __attribute__((ext_vector_type(8)));
typedef float f32x4 __attribute__((ext_vector_type(4)));

#define B_ 4
#define T_ 1024
#define NX_ 1024
#define NH_ 16
#define HD_ 64

__device__ __forceinline__ void gld16(const void* g, void* l) {
  __builtin_amdgcn_global_load_lds((const __attribute__((address_space(1))) void*)g,
                                   (__attribute__((address_space(3))) void*)l, 16, 0, 0);
}

// ---------- prep: contiguous fp32 -> bf16 ----------
__global__ __launch_bounds__(256) void k_cvt(const float* __restrict__ in, bf16* __restrict__ out, int n) {
  int i = (blockIdx.x * 256 + threadIdx.x) * 4;
  if (i + 3 < n) {
    float4 v = *(const float4*)(in + i);
    out[i] = (bf16)v.x; out[i + 1] = (bf16)v.y; out[i + 2] = (bf16)v.z; out[i + 3] = (bf16)v.w;
  }
}

// ---------- prep: (K,N) f32 -> (N,K) bf16 transpose ----------
__global__ __launch_bounds__(256) void k_transpose(const float* __restrict__ in, bf16* __restrict__ out, int K, int N) {
  __shared__ float tile[64][65];
  int n0 = blockIdx.x * 64, k0 = blockIdx.y * 64;
  for (int i = threadIdx.x; i < 4096; i += 256) {
    int r = i >> 6, c = i & 63;
    tile[r][c] = in[(size_t)(k0 + r) * N + n0 + c];
  }
  __syncthreads();
  for (int i = threadIdx.x; i < 4096; i += 256) {
    int r = i >> 6, c = i & 63;
    out[(size_t)(n0 + r) * K + k0 + c] = (bf16)tile[c][r];
  }
}

// ---------- 128x128 bf16 MFMA GEMM, BK=32, double-buffered global_load_lds ----------
// A: (M,K) row-major bf16. BT: (N,K) row-major bf16 (i.e. B transposed).
// EPI 0: qkv scatter-store (q,k head-major; v transposed to (bh,d,t)). EPI 1: fp32 out + bias.
template <int EPI>
__global__ __launch_bounds__(256) void k_gemm(
    const bf16* __restrict__ A, const bf16* __restrict__ BT, const float* __restrict__ bias,
    float* __restrict__ outF, bf16* __restrict__ qg, bf16* __restrict__ kg, bf16* __restrict__ vtg,
    int M, int N, int K) {
  __shared__ __align__(16) bf16 Ab[2][128 * 32];
  __shared__ __align__(16) bf16 Bb[2][128 * 32];
  int tid = threadIdx.x, lane = tid & 63, w = tid >> 6;
  int wm = w >> 1, wn = w & 1;
  int m0 = blockIdx.y * 128, n0 = blockIdx.x * 128;
  int sl = lane >> 4, lr = lane & 15;
  f32x4 acc[4][4] = {};
  int NKt = K >> 5;

  auto stage = [&](int kt, int bidx) {
    const bf16* Ag = A + (size_t)m0 * K + kt * 32;
    const bf16* Bg = BT + (size_t)n0 * K + kt * 32;
#pragma unroll
    for (int j = 0; j < 2; ++j) {
      int c = w * 128 + j * 64 + lane;
      int row = c >> 2, slot = c & 3;
      int ss = slot ^ ((row >> 1) & 3);  // bank-conflict swizzle, pre-applied on source
      gld16(Ag + (size_t)row * K + ss * 8, &Ab[bidx][(w * 128 + j * 64) * 8]);
      gld16(Bg + (size_t)row * K + ss * 8, &Bb[bidx][(w * 128 + j * 64) * 8]);
    }
  };
  stage(0, 0);
  for (int kt = 0; kt < NKt; ++kt) {
    int bidx = kt & 1;
    __syncthreads();
    if (kt + 1 < NKt) stage(kt + 1, bidx ^ 1);
    bf16x8 af[4], bfv[4];
#pragma unroll
    for (int mi = 0; mi < 4; ++mi) {
      int row = wm * 64 + mi * 16 + lr;
      af[mi] = *(const bf16x8*)&Ab[bidx][row * 32 + ((sl ^ ((row >> 1) & 3)) * 8)];
    }
#pragma unroll
    for (int ni = 0; ni < 4; ++ni) {
      int row = wn * 64 + ni * 16 + lr;
      bfv[ni] = *(const bf16x8*)&Bb[bidx][row * 32 + ((sl ^ ((row >> 1) & 3)) * 8)];
    }
#pragma unroll
    for (int mi = 0; mi < 4; ++mi)
#pragma unroll
      for (int ni = 0; ni < 4; ++ni)
        acc[mi][ni] = __builtin_amdgcn_mfma_f32_16x16x32_bf16(af[mi], bfv[ni], acc[mi][ni], 0, 0, 0);
  }
#pragma unroll
  for (int ni = 0; ni < 4; ++ni) {
    int n = n0 + wn * 64 + ni * 16 + lr;
    float bv = bias[n];
#pragma unroll
    for (int mi = 0; mi < 4; ++mi) {
      int mb = m0 + wm * 64 + mi * 16 + sl * 4;
#pragma unroll
      for (int r = 0; r < 4; ++r) {
        float v = acc[mi][ni][r] + bv;
        int m = mb + r;
        if (EPI == 0) {
          int region = n >> 10, hh = (n & 1023) >> 6, d = n & 63;
          int bb = m >> 10, t = m & 1023;
          int bh = bb * NH_ + hh;
          if (region == 0)      qg[((size_t)bh * T_ + t) * HD_ + d] = (bf16)v;
          else if (region == 1) kg[((size_t)bh * T_ + t) * HD_ + d] = (bf16)v;
          else                  vtg[((size_t)bh * HD_ + d) * T_ + t] = (bf16)v;
        } else {
          outF[(size_t)m * N + n] = v;
        }
      }
    }
  }
}

// ---------- fused causal attention with relative bias + bucketed rel-values ----------
// Single-pass unnormalized softmax (|S| << 80 for these inputs), normalize at epilogue.
__global__ __launch_bounds__(256) void k_attn(
    const bf16* __restrict__ qg, const bf16* __restrict__ kg, const bf16* __restrict__ vtg,
    const int* __restrict__ rel, const float* __restrict__ rel_weights,
    const int* __restrict__ rel_ids, const float* __restrict__ rel_values,
    bf16* __restrict__ ret) {
  __shared__ __align__(16) char smem[41 * 1024];
  bf16* Kt = (bf16*)smem;                 // 8KB  [s][d], XOR-swizzled
  bf16* Vt = (bf16*)(smem + 8192);        // 8KB  [d][s], XOR-swizzled
  bf16* Pt = (bf16*)(smem + 16384);       // 8KB  [t][s], XOR-swizzled
  float* prel = (float*)(smem + 24576);   // 16KB [t][64] bucket accumulators
  float* relw = (float*)(smem + 40960);   // 256B rel_weights column h
  float* rv = (float*)smem;               // epilogue overlay (16KB rel_values)

  int bx = blockIdx.x;
  int tq = bx & 15, h = (bx >> 4) & 15, b = bx >> 8;
  int bh = b * NH_ + h;
  int tid = threadIdx.x, lane = tid & 63, w = tid >> 6;
  int sl = lane >> 4, lr = lane & 15;

  for (int i = tid; i < 4096; i += 256) prel[i] = 0.f;
  if (tid < 64) relw[tid] = rel_weights[tid * NH_ + h];

  // Q fragments stay in registers for the whole s-loop (A-frag row = lane&15)
  int trowA = tq * 64 + w * 16 + lr;
  const bf16* qrow = qg + ((size_t)bh * T_ + trowA) * HD_;
  bf16x8 qf0 = *(const bf16x8*)(qrow + sl * 8);
  bf16x8 qf1 = *(const bf16x8*)(qrow + 32 + sl * 8);

  f32x4 O[4] = {};
  float lsum[4] = {0.f, 0.f, 0.f, 0.f};
  const int* relb = rel + (size_t)b * T_ * T_;
  __syncthreads();

  for (int st = 0; st <= tq; ++st) {
    int s0 = st * 64;
    const bf16* kbase = kg + ((size_t)bh * T_ + s0) * HD_;
    const bf16* vbase = vtg + (size_t)bh * HD_ * T_ + s0;
#pragma unroll
    for (int j = 0; j < 2; ++j) {
      int c = w * 128 + j * 64 + lane;             // 0..511 chunk of 16B
      int row = c >> 3, slot = c & 7, ss = slot ^ (row & 7);
      gld16(kbase + (size_t)row * HD_ + ss * 8, Kt + (w * 128 + j * 64) * 8);
      gld16(vbase + (size_t)row * T_ + ss * 8, Vt + (w * 128 + j * 64) * 8);
    }
    __syncthreads();

    // S = Q K^T
    f32x4 S[4];
#pragma unroll
    for (int ni = 0; ni < 4; ++ni) {
      int row = ni * 16 + lr;
      bf16x8 kb0 = *(const bf16x8*)&Kt[row * 64 + ((sl ^ (row & 7)) * 8)];
      bf16x8 kb1 = *(const bf16x8*)&Kt[row * 64 + (((4 + sl) ^ (row & 7)) * 8)];
      f32x4 a = {};
      a = __builtin_amdgcn_mfma_f32_16x16x32_bf16(qf0, kb0, a, 0, 0, 0);
      a = __builtin_amdgcn_mfma_f32_16x16x32_bf16(qf1, kb1, a, 0, 0, 0);
      S[ni] = a;
    }
    // scale + relative bias + causal mask + exp (unnormalized)
#pragma unroll
    for (int ni = 0; ni < 4; ++ni) {
      int s = s0 + ni * 16 + lr;
#pragma unroll
      for (int r = 0; r < 4; ++r) {
        int t = tq * 64 + w * 16 + sl * 4 + r;
        float val = S[ni][r] * 0.125f + relw[relb[(size_t)t * T_ + s]];
        float e = (s <= t) ? __expf(val) : 0.f;
        S[ni][r] = e;
        lsum[r] += e;
      }
    }
    // P -> LDS (wave-local rows), bf16, swizzled
#pragma unroll
    for (int ni = 0; ni < 4; ++ni) {
      int scol = ni * 16 + lr;
      int slot = scol >> 3, off = scol & 7;
#pragma unroll
      for (int r = 0; r < 4; ++r) {
        int prow = w * 16 + sl * 4 + r;
        Pt[prow * 64 + ((slot ^ (prow & 7)) * 8) + off] = (bf16)S[ni][r];
      }
    }
    // bucket accumulation: prel[t][rel_ids[t,s]] += e
#pragma unroll
    for (int ni = 0; ni < 4; ++ni) {
      int s = s0 + ni * 16 + lr;
#pragma unroll
      for (int r = 0; r < 4; ++r) {
        int t = tq * 64 + w * 16 + sl * 4 + r;
        if (s <= t)
          atomicAdd(&prel[(w * 16 + sl * 4 + r) * 64 + rel_ids[(size_t)t * T_ + s]], S[ni][r]);
      }
    }
    // O += P V
    {
      int prow = w * 16 + lr;
      bf16x8 pa0 = *(const bf16x8*)&Pt[prow * 64 + ((sl ^ (prow & 7)) * 8)];
      bf16x8 pa1 = *(const bf16x8*)&Pt[prow * 64 + (((4 + sl) ^ (prow & 7)) * 8)];
#pragma unroll
      for (int ni = 0; ni < 4; ++ni) {
        int d = ni * 16 + lr;
        bf16x8 vb0 = *(const bf16x8*)&Vt[d * 64 + ((sl ^ (d & 7)) * 8)];
        bf16x8 vb1 = *(const bf16x8*)&Vt[d * 64 + (((4 + sl) ^ (d & 7)) * 8)];
        O[ni] = __builtin_amdgcn_mfma_f32_16x16x32_bf16(pa0, vb0, O[ni], 0, 0, 0);
        O[ni] = __builtin_amdgcn_mfma_f32_16x16x32_bf16(pa1, vb1, O[ni], 0, 0, 0);
      }
    }
    __syncthreads();
  }

  // epilogue: rel_values into LDS overlay; row-sum reduce; add prel@rv; normalize; store
  for (int i = tid; i < 1024; i += 256)
    ((float4*)rv)[i] = ((const float4*)rel_values)[i];
  float inv[4];
#pragma unroll
  for (int r = 0; r < 4; ++r) {
    float v = lsum[r];
    v += __shfl_xor(v, 1); v += __shfl_xor(v, 2);
    v += __shfl_xor(v, 4); v += __shfl_xor(v, 8);
    inv[r] = 1.f / v;
  }
  __syncthreads();
#pragma unroll
  for (int r = 0; r < 4; ++r) {
    int tl = w * 16 + sl * 4 + r;
    int t = tq * 64 + tl;
    float racc[4] = {0.f, 0.f, 0.f, 0.f};
    for (int rr = 0; rr < 64; ++rr) {
      float p = prel[tl * 64 + rr];
#pragma unroll
      for (int ni = 0; ni < 4; ++ni)
        racc[ni] += p * rv[rr * 64 + ni * 16 + lr];
    }
#pragma unroll
    for (int ni = 0; ni < 4; ++ni) {
      float val = (O[ni][r] + racc[ni]) * inv[r];
      ret[((size_t)b * T_ + t) * NX_ + h * HD_ + ni * 16 + lr] = (bf16)val;
    }
  }
}

extern "C" void kernel_launch(void* const* d_in, const int* in_sizes, int n_in,
                              void* d_out, int out_size, void* d_ws, size_t ws_size,
                              hipStream_t stream) {
  const float* x = (const float*)d_in[0];
  const int* rel = (const int*)d_in[1];
  const float* w_attn = (const float*)d_in[2];
  const float* b_attn = (const float*)d_in[3];
  const float* w_proj = (const float*)d_in[4];
  const float* b_proj = (const float*)d_in[5];
  const float* rel_weights = (const float*)d_in[6];
  const float* rel_values = (const float*)d_in[7];
  const int* rel_ids = (const int*)d_in[8];
  float* out = (float*)d_out;

  char* ws = (char*)d_ws;
  bf16* xb  = (bf16*)(ws);                    //  8 MB: x as bf16 (4096x1024)
  bf16* wTa = (bf16*)(ws + 8388608);          //  6 MB: w_attn^T (3072x1024)
  bf16* wTp = (bf16*)(ws + 14680064);         //  2 MB: w_proj^T (1024x1024)
  bf16* qg  = (bf16*)(ws + 16777216);         //  8 MB: q (bh,t,d)
  bf16* kg  = (bf16*)(ws + 25165824);         //  8 MB: k (bh,t,d)
  bf16* vtg = (bf16*)(ws + 33554432);         //  8 MB: v^T (bh,d,t)
  bf16* ret = (bf16*)(ws + 41943040);         //  8 MB: attn out (b,t,nx)

  k_cvt<<<4096, 256, 0, stream>>>(x, xb, 4194304);
  k_transpose<<<dim3(48, 16), 256, 0, stream>>>(w_attn, wTa, 1024, 3072);
  k_transpose<<<dim3(16, 16), 256, 0, stream>>>(w_proj, wTp, 1024, 1024);
  k_gemm<0><<<dim3(24, 32), 256, 0, stream>>>(xb, wTa, b_attn, nullptr, qg, kg, vtg, 4096, 3072, 1024);
  k_attn<<<1024, 256, 0, stream>>>(qg, kg, vtg, rel, rel_weights, rel_ids, rel_values, ret);
  k_gemm<1><<<dim3(8, 32), 256, 0, stream>>>(ret, wTp, b_proj, out, nullptr, nullptr, nullptr, 4096, 1024, 1024);
}

// Round 5
// 565.610 us; speedup vs baseline: 1.2256x; 1.2256x over previous
//
#include <hip/hip_runtime.h>
#include <hip/hip_bf16.h>

typedef __bf16 bf16;
typedef __bf16 bf16x8 __attribute__((ext_vector_type(8)));
typedef float f32x4 __attribute__((ext_vector_type(4)));
typedef unsigned char u8;

#define B_ 4
#define T_ 1024
#define NX_ 1024
#define NH_ 16
#define HD_ 64

__device__ __forceinline__ void gld16(const void* g, void* l) {
  __builtin_amdgcn_global_load_lds((const __attribute__((address_space(1))) void*)g,
                                   (__attribute__((address_space(3))) void*)l, 16, 0, 0);
}

// ---------- prep: contiguous fp32 -> bf16 ----------
__global__ __launch_bounds__(256) void k_cvt(const float* __restrict__ in, bf16* __restrict__ out, int n) {
  int i = (blockIdx.x * 256 + threadIdx.x) * 4;
  if (i + 3 < n) {
    float4 v = *(const float4*)(in + i);
    out[i] = (bf16)v.x; out[i + 1] = (bf16)v.y; out[i + 2] = (bf16)v.z; out[i + 3] = (bf16)v.w;
  }
}

// ---------- prep: (K,N) f32 -> (N,K) bf16 transpose ----------
__global__ __launch_bounds__(256) void k_transpose(const float* __restrict__ in, bf16* __restrict__ out, int K, int N) {
  __shared__ float tile[64][65];
  int n0 = blockIdx.x * 64, k0 = blockIdx.y * 64;
  for (int i = threadIdx.x; i < 4096; i += 256) {
    int r = i >> 6, c = i & 63;
    tile[r][c] = in[(size_t)(k0 + r) * N + n0 + c];
  }
  __syncthreads();
  for (int i = threadIdx.x; i < 4096; i += 256) {
    int r = i >> 6, c = i & 63;
    out[(size_t)(n0 + r) * K + k0 + c] = (bf16)tile[c][r];
  }
}

// ---------- pack rel ids int32 -> u8, transposed [t][s] -> [s][t] ----------
// z<4: rel slab z (per-batch). z==4: rel_ids.
__global__ __launch_bounds__(256) void k_pack(const int* __restrict__ rel, const int* __restrict__ rel_ids,
                                              u8* __restrict__ rel8T, u8* __restrict__ relid8T) {
  __shared__ u8 tile[64][64];
  int z = blockIdx.z;
  const int* src = (z < 4) ? rel + (size_t)z * T_ * T_ : rel_ids;
  u8* dst = (z < 4) ? rel8T + (size_t)z * T_ * T_ : relid8T;
  int t0 = blockIdx.y * 64, s0 = blockIdx.x * 64;
  int row = threadIdx.x >> 2, seg = (threadIdx.x & 3) * 16;
  const int4* p = (const int4*)(src + (size_t)(t0 + row) * T_ + s0 + seg);
#pragma unroll
  for (int j = 0; j < 4; ++j) {
    int4 v = p[j];
    tile[row][seg + j * 4 + 0] = (u8)v.x;
    tile[row][seg + j * 4 + 1] = (u8)v.y;
    tile[row][seg + j * 4 + 2] = (u8)v.z;
    tile[row][seg + j * 4 + 3] = (u8)v.w;
  }
  __syncthreads();
  u8 outv[16];
#pragma unroll
  for (int j = 0; j < 16; ++j) outv[j] = tile[seg + j][row];
  *(uint4*)(dst + (size_t)(s0 + row) * T_ + t0 + seg) = *(uint4*)outv;
}

// ---------- 128x128 bf16 MFMA GEMM, BK=32, double-buffered global_load_lds ----------
template <int EPI>
__global__ __launch_bounds__(256) void k_gemm(
    const bf16* __restrict__ A, const bf16* __restrict__ BT, const float* __restrict__ bias,
    float* __restrict__ outF, bf16* __restrict__ qg, bf16* __restrict__ kg, bf16* __restrict__ vtg,
    int M, int N, int K) {
  __shared__ __align__(16) bf16 Ab[2][128 * 32];
  __shared__ __align__(16) bf16 Bb[2][128 * 32];
  int tid = threadIdx.x, lane = tid & 63, w = tid >> 6;
  int wm = w >> 1, wn = w & 1;
  int m0 = blockIdx.y * 128, n0 = blockIdx.x * 128;
  int sl = lane >> 4, lr = lane & 15;
  f32x4 acc[4][4] = {};
  int NKt = K >> 5;

  auto stage = [&](int kt, int bidx) {
    const bf16* Ag = A + (size_t)m0 * K + kt * 32;
    const bf16* Bg = BT + (size_t)n0 * K + kt * 32;
#pragma unroll
    for (int j = 0; j < 2; ++j) {
      int c = w * 128 + j * 64 + lane;
      int row = c >> 2, slot = c & 3;
      int ss = slot ^ ((row >> 1) & 3);
      gld16(Ag + (size_t)row * K + ss * 8, &Ab[bidx][(w * 128 + j * 64) * 8]);
      gld16(Bg + (size_t)row * K + ss * 8, &Bb[bidx][(w * 128 + j * 64) * 8]);
    }
  };
  stage(0, 0);
  for (int kt = 0; kt < NKt; ++kt) {
    int bidx = kt & 1;
    __syncthreads();
    if (kt + 1 < NKt) stage(kt + 1, bidx ^ 1);
    bf16x8 af[4], bfv[4];
#pragma unroll
    for (int mi = 0; mi < 4; ++mi) {
      int row = wm * 64 + mi * 16 + lr;
      af[mi] = *(const bf16x8*)&Ab[bidx][row * 32 + ((sl ^ ((row >> 1) & 3)) * 8)];
    }
#pragma unroll
    for (int ni = 0; ni < 4; ++ni) {
      int row = wn * 64 + ni * 16 + lr;
      bfv[ni] = *(const bf16x8*)&Bb[bidx][row * 32 + ((sl ^ ((row >> 1) & 3)) * 8)];
    }
#pragma unroll
    for (int mi = 0; mi < 4; ++mi)
#pragma unroll
      for (int ni = 0; ni < 4; ++ni)
        acc[mi][ni] = __builtin_amdgcn_mfma_f32_16x16x32_bf16(af[mi], bfv[ni], acc[mi][ni], 0, 0, 0);
  }
#pragma unroll
  for (int ni = 0; ni < 4; ++ni) {
    int n = n0 + wn * 64 + ni * 16 + lr;
    float bv = bias[n];
#pragma unroll
    for (int mi = 0; mi < 4; ++mi) {
      int mb = m0 + wm * 64 + mi * 16 + sl * 4;
#pragma unroll
      for (int r = 0; r < 4; ++r) {
        float v = acc[mi][ni][r] + bv;
        int m = mb + r;
        if (EPI == 0) {
          int region = n >> 10, hh = (n & 1023) >> 6, d = n & 63;
          int bb = m >> 10, t = m & 1023;
          int bh = bb * NH_ + hh;
          if (region == 0)      qg[((size_t)bh * T_ + t) * HD_ + d] = (bf16)v;
          else if (region == 1) kg[((size_t)bh * T_ + t) * HD_ + d] = (bf16)v;
          else                  vtg[((size_t)bh * HD_ + d) * T_ + t] = (bf16)v;
        } else {
          outF[(size_t)m * N + n] = v;
        }
      }
    }
  }
}

// ---------- fused causal attention; all per-tile global traffic prefetched via gld16 ----------
__global__ __launch_bounds__(256) void k_attn(
    const bf16* __restrict__ qg, const bf16* __restrict__ kg, const bf16* __restrict__ vtg,
    const u8* __restrict__ rel8T, const float* __restrict__ rel_weights,
    const u8* __restrict__ relid8T, const float* __restrict__ rel_values,
    bf16* __restrict__ ret) {
  __shared__ __align__(16) bf16 Kt[2][4096];   // [s][d] swizzled, dbuf
  __shared__ __align__(16) bf16 Vt[2][4096];   // [d][s] swizzled, dbuf
  __shared__ __align__(16) u8 R8[2][4096];     // rel ids  [s][t], slot-swizzled, dbuf
  __shared__ __align__(16) u8 I8[2][4096];     // relid_v  [s][t], slot-swizzled, dbuf
  __shared__ __align__(16) bf16 Pt[4096];      // P tile   [t][s] swizzled (wave-local rows)
  __shared__ float prel[4096];                 // [t][64] bucket accumulators
  __shared__ float tabw[64];                   // exp(rel_weights[:,h])

  int bx = blockIdx.x;
  int tq = 15 - (bx & 15), h = (bx >> 4) & 15, b = bx >> 8;  // heavy tiles first
  int bh = b * NH_ + h;
  int tid = threadIdx.x, lane = tid & 63, w = tid >> 6;
  int sl = lane >> 4, lr = lane & 15;
  int tb4 = w * 16 + sl * 4;

  for (int i = tid; i < 4096; i += 256) prel[i] = 0.f;
  if (tid < 64) tabw[tid] = __expf(rel_weights[tid * NH_ + h]);

  int trowA = tq * 64 + w * 16 + lr;
  const bf16* qrow = qg + ((size_t)bh * T_ + trowA) * HD_;
  bf16x8 qf0 = *(const bf16x8*)(qrow + sl * 8);
  bf16x8 qf1 = *(const bf16x8*)(qrow + 32 + sl * 8);

  const u8* relb8 = rel8T + (size_t)b * T_ * T_ + tq * 64;
  const u8* idb8 = relid8T + tq * 64;

  auto stage = [&](int st, int bidx) {
    int s0 = st * 64;
    const bf16* kbase = kg + ((size_t)bh * T_ + s0) * HD_;
    const bf16* vbase = vtg + (size_t)bh * HD_ * T_ + s0;
#pragma unroll
    for (int j = 0; j < 2; ++j) {
      int c = w * 128 + j * 64 + lane;
      int row = c >> 3, slot = c & 7, ss = slot ^ (row & 7);
      gld16(kbase + (size_t)row * HD_ + ss * 8, &Kt[bidx][(w * 128 + j * 64) * 8]);
      gld16(vbase + (size_t)row * T_ + ss * 8, &Vt[bidx][(w * 128 + j * 64) * 8]);
    }
    int c2 = w * 64 + lane;
    int r2 = c2 >> 2, sl2 = c2 & 3, ss2 = sl2 ^ (r2 & 3);
    gld16(relb8 + (size_t)(s0 + r2) * T_ + ss2 * 16, &R8[bidx][w * 1024]);
    gld16(idb8 + (size_t)(s0 + r2) * T_ + ss2 * 16, &I8[bidx][w * 1024]);
  };

  f32x4 O[4] = {};
  float lsum[4] = {0.f, 0.f, 0.f, 0.f};

  stage(0, 0);
  for (int st = 0; st <= tq; ++st) {
    int cur = st & 1;
    int s0 = st * 64;
    __syncthreads();  // buf cur complete (vmcnt drain), prev consumers done
    if (st < tq) stage(st + 1, cur ^ 1);  // loads fly during this tile's compute

    // S = Q K^T
    f32x4 S[4];
#pragma unroll
    for (int ni = 0; ni < 4; ++ni) {
      int row = ni * 16 + lr;
      bf16x8 kb0 = *(const bf16x8*)&Kt[cur][row * 64 + ((sl ^ (row & 7)) * 8)];
      bf16x8 kb1 = *(const bf16x8*)&Kt[cur][row * 64 + (((4 + sl) ^ (row & 7)) * 8)];
      f32x4 a = {};
      a = __builtin_amdgcn_mfma_f32_16x16x32_bf16(qf0, kb0, a, 0, 0, 0);
      a = __builtin_amdgcn_mfma_f32_16x16x32_bf16(qf1, kb1, a, 0, 0, 0);
      S[ni] = a;
    }

    // exp(S/8)*tab[rel_id], mask, P->LDS, bucket accumulate (all LDS-fed)
#pragma unroll
    for (int ni = 0; ni < 4; ++ni) {
      int s_local = ni * 16 + lr;
      int s = s0 + s_local;
      int idoff = s_local * 64 + ((w ^ (s_local & 3)) << 4) + sl * 4;
      unsigned rid4 = *(const unsigned*)&R8[cur][idoff];
      unsigned iid4 = *(const unsigned*)&I8[cur][idoff];
#pragma unroll
      for (int r = 0; r < 4; ++r) {
        int t = tq * 64 + tb4 + r;
        float e = (s <= t) ? __expf(S[ni][r] * 0.125f) * tabw[(rid4 >> (8 * r)) & 63] : 0.f;
        S[ni][r] = e;
        lsum[r] += e;
      }
      int slot = s_local >> 3, off = s_local & 7;
#pragma unroll
      for (int r = 0; r < 4; ++r) {
        int prow = tb4 + r;
        Pt[prow * 64 + ((slot ^ (prow & 7)) * 8) + off] = (bf16)S[ni][r];
        if (S[ni][r] != 0.f)
          atomicAdd(&prel[prow * 64 + ((iid4 >> (8 * r)) & 63)], S[ni][r]);
      }
    }

    // O += P V  (wave-local Pt rows)
    {
      int prow = w * 16 + lr;
      bf16x8 pa0 = *(const bf16x8*)&Pt[prow * 64 + ((sl ^ (prow & 7)) * 8)];
      bf16x8 pa1 = *(const bf16x8*)&Pt[prow * 64 + (((4 + sl) ^ (prow & 7)) * 8)];
#pragma unroll
      for (int ni = 0; ni < 4; ++ni) {
        int d = ni * 16 + lr;
        bf16x8 vb0 = *(const bf16x8*)&Vt[cur][d * 64 + ((sl ^ (d & 7)) * 8)];
        bf16x8 vb1 = *(const bf16x8*)&Vt[cur][d * 64 + (((4 + sl) ^ (d & 7)) * 8)];
        O[ni] = __builtin_amdgcn_mfma_f32_16x16x32_bf16(pa0, vb0, O[ni], 0, 0, 0);
        O[ni] = __builtin_amdgcn_mfma_f32_16x16x32_bf16(pa1, vb1, O[ni], 0, 0, 0);
      }
    }
  }

  // epilogue: rel_values overlay on Kt, row-sum reduce, prel@rv, normalize, store
  __syncthreads();
  float* rv = (float*)&Kt[0][0];
  for (int i = tid; i < 1024; i += 256)
    ((float4*)rv)[i] = ((const float4*)rel_values)[i];
  float inv[4];
#pragma unroll
  for (int r = 0; r < 4; ++r) {
    float v = lsum[r];
    v += __shfl_xor(v, 1); v += __shfl_xor(v, 2);
    v += __shfl_xor(v, 4); v += __shfl_xor(v, 8);
    inv[r] = 1.f / v;
  }
  __syncthreads();
#pragma unroll
  for (int r = 0; r < 4; ++r) {
    int tl = tb4 + r;
    int t = tq * 64 + tl;
    float racc[4] = {0.f, 0.f, 0.f, 0.f};
    for (int rr = 0; rr < 64; ++rr) {
      float p = prel[tl * 64 + rr];
#pragma unroll
      for (int ni = 0; ni < 4; ++ni)
        racc[ni] += p * rv[rr * 64 + ni * 16 + lr];
    }
#pragma unroll
    for (int ni = 0; ni < 4; ++ni) {
      float val = (O[ni][r] + racc[ni]) * inv[r];
      ret[((size_t)b * T_ + t) * NX_ + h * HD_ + ni * 16 + lr] = (bf16)val;
    }
  }
}

extern "C" void kernel_launch(void* const* d_in, const int* in_sizes, int n_in,
                              void* d_out, int out_size, void* d_ws, size_t ws_size,
                              hipStream_t stream) {
  const float* x = (const float*)d_in[0];
  const int* rel = (const int*)d_in[1];
  const float* w_attn = (const float*)d_in[2];
  const float* b_attn = (const float*)d_in[3];
  const float* w_proj = (const float*)d_in[4];
  const float* b_proj = (const float*)d_in[5];
  const float* rel_weights = (const float*)d_in[6];
  const float* rel_values = (const float*)d_in[7];
  const int* rel_ids = (const int*)d_in[8];
  float* out = (float*)d_out;

  char* ws = (char*)d_ws;
  bf16* xb  = (bf16*)(ws);                    //  8 MB: x as bf16 (consumed by gemm<0>)
  bf16* wTa = (bf16*)(ws + 8388608);          //  6 MB: w_attn^T
  bf16* wTp = (bf16*)(ws + 14680064);         //  2 MB: w_proj^T
  bf16* qg  = (bf16*)(ws + 16777216);         //  8 MB: q (bh,t,d)
  bf16* kg  = (bf16*)(ws + 25165824);         //  8 MB: k (bh,t,d)
  bf16* vtg = (bf16*)(ws + 33554432);         //  8 MB: v^T (bh,d,t)
  bf16* ret = (bf16*)(ws + 41943040);         //  8 MB: attn out (b,t,nx)
  // packed u8 id planes overlay the dead xb region after gemm<0> consumed it
  u8* rel8T   = (u8*)(ws);                    //  4 MB: rel  ids u8, [b][s][t]
  u8* relid8T = (u8*)(ws + 4194304);          //  1 MB: rel_ids u8, [s][t]

  k_cvt<<<4096, 256, 0, stream>>>(x, xb, 4194304);
  k_transpose<<<dim3(48, 16), 256, 0, stream>>>(w_attn, wTa, 1024, 3072);
  k_transpose<<<dim3(16, 16), 256, 0, stream>>>(w_proj, wTp, 1024, 1024);
  k_gemm<0><<<dim3(24, 32), 256, 0, stream>>>(xb, wTa, b_attn, nullptr, qg, kg, vtg, 4096, 3072, 1024);
  k_pack<<<dim3(16, 16, 5), 256, 0, stream>>>(rel, rel_ids, rel8T, relid8T);
  k_attn<<<1024, 256, 0, stream>>>(qg, kg, vtg, rel8T, rel_weights, relid8T, rel_values, ret);
  k_gemm<1><<<dim3(8, 32), 256, 0, stream>>>(ret, wTp, b_proj, out, nullptr, nullptr, nullptr, 4096, 1024, 1024);
}

// Round 6
// 451.246 us; speedup vs baseline: 1.5363x; 1.2534x over previous
//
#include <hip/hip_runtime.h>
#include <hip/hip_bf16.h>

typedef __bf16 bf16;
typedef __bf16 bf16x8 __attribute__((ext_vector_type(8)));
typedef float f32x4 __attribute__((ext_vector_type(4)));
typedef unsigned char u8;
typedef unsigned int u32;
typedef unsigned short u16;
typedef u16 ushort8 __attribute__((ext_vector_type(8)));

#define B_ 4
#define T_ 1024
#define NX_ 1024
#define NH_ 16
#define HD_ 64

__device__ __forceinline__ void gld16(const void* g, void* l) {
  __builtin_amdgcn_global_load_lds((const __attribute__((address_space(1))) void*)g,
                                   (__attribute__((address_space(3))) void*)l, 16, 0, 0);
}

// ---------- prep: contiguous fp32 -> bf16 ----------
__global__ __launch_bounds__(256) void k_cvt(const float* __restrict__ in, bf16* __restrict__ out, int n) {
  int i = (blockIdx.x * 256 + threadIdx.x) * 4;
  if (i + 3 < n) {
    float4 v = *(const float4*)(in + i);
    out[i] = (bf16)v.x; out[i + 1] = (bf16)v.y; out[i + 2] = (bf16)v.z; out[i + 3] = (bf16)v.w;
  }
}

// ---------- prep: (K,N) f32 -> (N,K) bf16 transpose ----------
__global__ __launch_bounds__(256) void k_transpose(const float* __restrict__ in, bf16* __restrict__ out, int K, int N) {
  __shared__ float tile[64][65];
  int n0 = blockIdx.x * 64, k0 = blockIdx.y * 64;
  for (int i = threadIdx.x; i < 4096; i += 256) {
    int r = i >> 6, c = i & 63;
    tile[r][c] = in[(size_t)(k0 + r) * N + n0 + c];
  }
  __syncthreads();
  for (int i = threadIdx.x; i < 4096; i += 256) {
    int r = i >> 6, c = i & 63;
    out[(size_t)(n0 + r) * K + k0 + c] = (bf16)tile[c][r];
  }
}

// ---------- pack int32 ids -> u8 (natural [t][s] layout; no transpose needed) ----------
// dst8 covers rel (4MB) then rel_ids (1MB) contiguously.
__global__ __launch_bounds__(256) void k_pack(const int* __restrict__ rel, const int* __restrict__ rel_ids,
                                              u8* __restrict__ dst8) {
  int i = (blockIdx.x * 256 + threadIdx.x) * 4;
  const int* src = (i < 4194304) ? (rel + i) : (rel_ids + (i - 4194304));
  int4 v = *(const int4*)src;
  uchar4 o = {(u8)v.x, (u8)v.y, (u8)v.z, (u8)v.w};
  *(uchar4*)(dst8 + i) = o;
}

// ---------- 128x128 bf16 MFMA GEMM, BK=32, double-buffered global_load_lds ----------
template <int EPI>
__global__ __launch_bounds__(256) void k_gemm(
    const bf16* __restrict__ A, const bf16* __restrict__ BT, const float* __restrict__ bias,
    float* __restrict__ outF, bf16* __restrict__ qg, bf16* __restrict__ kg, bf16* __restrict__ vtg,
    int M, int N, int K) {
  __shared__ __align__(16) bf16 Ab[2][128 * 32];
  __shared__ __align__(16) bf16 Bb[2][128 * 32];
  int tid = threadIdx.x, lane = tid & 63, w = tid >> 6;
  int wm = w >> 1, wn = w & 1;
  int m0 = blockIdx.y * 128, n0 = blockIdx.x * 128;
  int sl = lane >> 4, lr = lane & 15;
  f32x4 acc[4][4] = {};
  int NKt = K >> 5;

  auto stage = [&](int kt, int bidx) {
    const bf16* Ag = A + (size_t)m0 * K + kt * 32;
    const bf16* Bg = BT + (size_t)n0 * K + kt * 32;
#pragma unroll
    for (int j = 0; j < 2; ++j) {
      int c = w * 128 + j * 64 + lane;
      int row = c >> 2, slot = c & 3;
      int ss = slot ^ ((row >> 1) & 3);
      gld16(Ag + (size_t)row * K + ss * 8, &Ab[bidx][(w * 128 + j * 64) * 8]);
      gld16(Bg + (size_t)row * K + ss * 8, &Bb[bidx][(w * 128 + j * 64) * 8]);
    }
  };
  stage(0, 0);
  for (int kt = 0; kt < NKt; ++kt) {
    int bidx = kt & 1;
    __syncthreads();
    if (kt + 1 < NKt) stage(kt + 1, bidx ^ 1);
    bf16x8 af[4], bfv[4];
#pragma unroll
    for (int mi = 0; mi < 4; ++mi) {
      int row = wm * 64 + mi * 16 + lr;
      af[mi] = *(const bf16x8*)&Ab[bidx][row * 32 + ((sl ^ ((row >> 1) & 3)) * 8)];
    }
#pragma unroll
    for (int ni = 0; ni < 4; ++ni) {
      int row = wn * 64 + ni * 16 + lr;
      bfv[ni] = *(const bf16x8*)&Bb[bidx][row * 32 + ((sl ^ ((row >> 1) & 3)) * 8)];
    }
#pragma unroll
    for (int mi = 0; mi < 4; ++mi)
#pragma unroll
      for (int ni = 0; ni < 4; ++ni)
        acc[mi][ni] = __builtin_amdgcn_mfma_f32_16x16x32_bf16(af[mi], bfv[ni], acc[mi][ni], 0, 0, 0);
  }
#pragma unroll
  for (int ni = 0; ni < 4; ++ni) {
    int n = n0 + wn * 64 + ni * 16 + lr;
    float bv = bias[n];
#pragma unroll
    for (int mi = 0; mi < 4; ++mi) {
      int mb = m0 + wm * 64 + mi * 16 + sl * 4;
#pragma unroll
      for (int r = 0; r < 4; ++r) {
        float v = acc[mi][ni][r] + bv;
        int m = mb + r;
        if (EPI == 0) {
          int region = n >> 10, hh = (n & 1023) >> 6, d = n & 63;
          int bb = m >> 10, t = m & 1023;
          int bh = bb * NH_ + hh;
          if (region == 0)      qg[((size_t)bh * T_ + t) * HD_ + d] = (bf16)v;
          else if (region == 1) kg[((size_t)bh * T_ + t) * HD_ + d] = (bf16)v;
          else                  vtg[((size_t)bh * HD_ + d) * T_ + t] = (bf16)v;
        } else {
          outF[(size_t)m * N + n] = v;
        }
      }
    }
  }
}

// ---------- wave-independent fused attention: 1 wave per 16-row Q strip ----------
// No __syncthreads anywhere. Per-wave LDS, 2-deep gld16 prefetch with counted vmcnt.
// Swapped MFMA: S^T = mfma(K, Q)  (lane: t = lane&15, s = si*16 + sl*4 + r)
//               O^T = mfma(V^T, P^T) (lane: t = lane&15, d = ni*16 + sl*4 + r)
__global__ __launch_bounds__(64) void k_attn(
    const bf16* __restrict__ qg, const bf16* __restrict__ kg, const bf16* __restrict__ vtg,
    const u8* __restrict__ rel8, const float* __restrict__ rel_weights,
    const u8* __restrict__ relid8, const float* __restrict__ rel_values,
    bf16* __restrict__ ret) {
  __shared__ __align__(16) char smem[23808];
  char* KB = smem;                        // 2 x 4KB : K  [32s][64d] bf16, slot^= (s&7)
  char* VB = smem + 8192;                 // 2 x 4KB : V^T[64d][32s] bf16, slot^= (d&3)
  char* PB = smem + 16384;                // 1KB     : P  [16t][32s] bf16, slot^= (t&3)
  char* IDS = smem + 17408;               // 2 x 1KB : R8[16t][32s] | I8[16t][32s]
  float* prel = (float*)(smem + 19456);   // 4KB     : [16t][64] bucket accumulators
  float* tab = (float*)(smem + 23552);    // 256B    : exp(rel_weights[:,h])

  int bx = blockIdx.x;
  int tt = 63 - (bx & 63);                // heavy strips first
  int h = (bx >> 6) & 15, b = bx >> 10;
  int bh = b * NH_ + h;
  int t0 = tt * 16;
  int lane = threadIdx.x;
  int lr = lane & 15, sl = lane >> 4;

  tab[lane] = __expf(rel_weights[lane * NH_ + h]);
#pragma unroll
  for (int i = 0; i < 4; ++i) ((float4*)prel)[lane + 64 * i] = float4{0.f, 0.f, 0.f, 0.f};

  // Q fragments (B-operand: col t = lr, k = d)
  const bf16* qrow = qg + ((size_t)bh * T_ + t0 + lr) * HD_;
  bf16x8 qf0 = *(const bf16x8*)(qrow + sl * 8);
  bf16x8 qf1 = *(const bf16x8*)(qrow + 32 + sl * 8);

  const u8* rel8n = rel8 + (size_t)b * T_ * T_;

  // staging lane constants (source pre-swizzled, LDS dest linear: rule 21)
  int krow = lane >> 3;                     // 0..7
  int kss = (lane & 7) ^ krow;              // K d-slot swizzle
  int vd = lane >> 2;                       // 0..15
  int vss = (lane & 3) ^ (vd & 3);          // V s-slot swizzle
  int itl = (lane & 31) >> 1, ihalf = lane & 1;
  const u8* isrc = ((lane < 32) ? rel8n : relid8) + (size_t)(t0 + itl) * T_ + ihalf * 16;

  auto stage = [&](int st, int bidx) {
    int s0 = st * 32;
    const bf16* kb = kg + ((size_t)bh * T_ + s0 + krow) * HD_ + kss * 8;
#pragma unroll
    for (int g = 0; g < 4; ++g)
      gld16(kb + (size_t)(g * 8) * HD_, KB + bidx * 4096 + g * 1024);
    const bf16* vb = vtg + ((size_t)bh * HD_ + vd) * T_ + s0 + vss * 8;
#pragma unroll
    for (int g = 0; g < 4; ++g)
      gld16(vb + (size_t)(g * 16) * T_, VB + bidx * 4096 + g * 1024);
    gld16(isrc + s0, IDS + bidx * 1024);
  };

  f32x4 acc[4] = {};
  float lsum = 0.f;
  int n = (tt >> 1) + 1;                    // s-tiles of 32 covering s <= t0+15

  stage(0, 0);
  for (int st = 0; st < n; ++st) {
    int cur = st & 1;
    int s0 = st * 32;
    asm volatile("s_waitcnt lgkmcnt(0)" ::: "memory");  // prior ds reads of buf cur^1 done
    if (st + 1 < n) {
      stage(st + 1, cur ^ 1);
      asm volatile("s_waitcnt vmcnt(9)" ::: "memory");  // buf cur complete; next 9 in flight
    } else {
      asm volatile("s_waitcnt vmcnt(0)" ::: "memory");
    }
    __builtin_amdgcn_sched_barrier(0);

    const char* KBc = KB + cur * 4096;
    // S^T = K * Q
    f32x4 S[2] = {};
#pragma unroll
    for (int si = 0; si < 2; ++si) {
      int srow = si * 16 + lr;
#pragma unroll
      for (int dsi = 0; dsi < 2; ++dsi) {
        bf16x8 ka = *(const bf16x8*)(KBc + srow * 128 + (((dsi * 4 + sl) ^ (lr & 7)) * 16));
        S[si] = __builtin_amdgcn_mfma_f32_16x16x32_bf16(ka, dsi ? qf1 : qf0, S[si], 0, 0, 0);
      }
    }
    // exp(S/8)*tab[rel], mask, P write (8B packed), bucket atomics
    int tglob = t0 + lr;
#pragma unroll
    for (int si = 0; si < 2; ++si) {
      int sbase = s0 + si * 16 + sl * 4;
      u32 rid = *(const u32*)(IDS + cur * 1024 + lr * 32 + si * 16 + sl * 4);
      u32 iid = *(const u32*)(IDS + cur * 1024 + 512 + lr * 32 + si * 16 + sl * 4);
      u16 pb4[4];
#pragma unroll
      for (int r = 0; r < 4; ++r) {
        float e = (sbase + r <= tglob) ? __expf(S[si][r] * 0.125f) * tab[(rid >> (8 * r)) & 63] : 0.f;
        lsum += e;
        bf16 eb = (bf16)e;
        pb4[r] = *(u16*)&eb;
        if (e != 0.f) atomicAdd(&prel[lr * 64 + ((iid >> (8 * r)) & 63)], e);
      }
      int slot = (si * 2 + (sl >> 1)) ^ (lr & 3);
      *(uint2*)(PB + lr * 64 + slot * 16 + (sl & 1) * 8) =
          uint2{(u32)pb4[0] | ((u32)pb4[1] << 16), (u32)pb4[2] | ((u32)pb4[3] << 16)};
    }
    // O^T += V^T * P^T
    bf16x8 pbf = *(const bf16x8*)(PB + lr * 64 + ((sl ^ (lr & 3)) * 16));
    const char* VBc = VB + cur * 4096;
#pragma unroll
    for (int ni = 0; ni < 4; ++ni) {
      int d = ni * 16 + lr;
      bf16x8 va = *(const bf16x8*)(VBc + d * 64 + ((sl ^ (lr & 3)) * 16));
      acc[ni] = __builtin_amdgcn_mfma_f32_16x16x32_bf16(va, pbf, acc[ni], 0, 0, 0);
    }
  }

  // ---- epilogue (wave-local) ----
  float v = lsum;
  v += __shfl_xor(v, 16);
  v += __shfl_xor(v, 32);
  float inv = 1.f / v;                      // lane lr holds inv for t = lr

  // O^T -> Obuf[16][68] f32 (KB area), read back in [t][d] orientation
  asm volatile("s_waitcnt lgkmcnt(0)" ::: "memory");
  __builtin_amdgcn_sched_barrier(0);
  float* ob = (float*)KB;
#pragma unroll
  for (int ni = 0; ni < 4; ++ni)
#pragma unroll
    for (int r = 0; r < 4; ++r)
      ob[lr * 68 + ni * 16 + sl * 4 + r] = acc[ni][r];

  int th = lane >> 2, q = lane & 3;         // lane owns (t=th, d = q*16 .. q*16+15)
  f32x4 o[4], racc[4] = {};
#pragma unroll
  for (int i = 0; i < 4; ++i)
    o[i] = *(const f32x4*)&ob[th * 68 + q * 16 + i * 4];
  float invt = __shfl(inv, th);

  // rel-values term: racc[t][d] = sum_rr prel[t][rr] * rel_values[rr][d], rv staged in 2 halves
  float* rvb = (float*)VB;
#pragma unroll
  for (int p = 0; p < 2; ++p) {
    asm volatile("s_waitcnt lgkmcnt(0)" ::: "memory");  // VB ds reads done before overwrite
    __builtin_amdgcn_sched_barrier(0);
#pragma unroll
    for (int g = 0; g < 8; ++g)
      gld16(rel_values + p * 2048 + g * 256 + lane * 4, VB + g * 1024);
    asm volatile("s_waitcnt vmcnt(0)" ::: "memory");
    __builtin_amdgcn_sched_barrier(0);
    for (int rr = 0; rr < 32; ++rr) {
      float pv = prel[th * 64 + p * 32 + rr];
#pragma unroll
      for (int i = 0; i < 4; ++i)
        racc[i] += pv * *(const f32x4*)&rvb[rr * 64 + q * 16 + i * 4];
    }
  }

  u16 outv[16];
#pragma unroll
  for (int i = 0; i < 4; ++i)
#pragma unroll
    for (int j = 0; j < 4; ++j) {
      bf16 ob16 = (bf16)((o[i][j] + racc[i][j]) * invt);
      outv[i * 4 + j] = *(u16*)&ob16;
    }
  bf16* rp = ret + ((size_t)(b * T_ + t0 + th) * NX_ + h * HD_ + q * 16);
  *(ushort8*)rp = *(ushort8*)&outv[0];
  *(ushort8*)(rp + 8) = *(ushort8*)&outv[8];
}

extern "C" void kernel_launch(void* const* d_in, const int* in_sizes, int n_in,
                              void* d_out, int out_size, void* d_ws, size_t ws_size,
                              hipStream_t stream) {
  const float* x = (const float*)d_in[0];
  const int* rel = (const int*)d_in[1];
  const float* w_attn = (const float*)d_in[2];
  const float* b_attn = (const float*)d_in[3];
  const float* w_proj = (const float*)d_in[4];
  const float* b_proj = (const float*)d_in[5];
  const float* rel_weights = (const float*)d_in[6];
  const float* rel_values = (const float*)d_in[7];
  const int* rel_ids = (const int*)d_in[8];
  float* out = (float*)d_out;

  char* ws = (char*)d_ws;
  bf16* xb  = (bf16*)(ws);                    //  8 MB: x as bf16 (consumed by gemm<0>)
  bf16* wTa = (bf16*)(ws + 8388608);          //  6 MB: w_attn^T
  bf16* wTp = (bf16*)(ws + 14680064);         //  2 MB: w_proj^T
  bf16* qg  = (bf16*)(ws + 16777216);         //  8 MB: q (bh,t,d)
  bf16* kg  = (bf16*)(ws + 25165824);         //  8 MB: k (bh,t,d)
  bf16* vtg = (bf16*)(ws + 33554432);         //  8 MB: v^T (bh,d,t)
  bf16* ret = (bf16*)(ws + 41943040);         //  8 MB: attn out (b,t,nx)
  // packed u8 id planes overlay the dead xb region after gemm<0> consumed it
  u8* rel8   = (u8*)(ws);                     //  4 MB: rel  ids u8, [b][t][s]
  u8* relid8 = (u8*)(ws + 4194304);           //  1 MB: rel_ids u8, [t][s]

  k_cvt<<<4096, 256, 0, stream>>>(x, xb, 4194304);
  k_transpose<<<dim3(48, 16), 256, 0, stream>>>(w_attn, wTa, 1024, 3072);
  k_transpose<<<dim3(16, 16), 256, 0, stream>>>(w_proj, wTp, 1024, 1024);
  k_gemm<0><<<dim3(24, 32), 256, 0, stream>>>(xb, wTa, b_attn, nullptr, qg, kg, vtg, 4096, 3072, 1024);
  k_pack<<<5120, 256, 0, stream>>>(rel, rel_ids, rel8);
  k_attn<<<4096, 64, 0, stream>>>(qg, kg, vtg, rel8, rel_weights, relid8, rel_values, ret);
  k_gemm<1><<<dim3(8, 32), 256, 0, stream>>>(ret, wTp, b_proj, out, nullptr, nullptr, nullptr, 4096, 1024, 1024);
}